// Round 6
// baseline (314.220 us; speedup 1.0000x reference)
//
#include <hip/hip_runtime.h>

#define NN 1024
#define MM 1022          // interior size
#define PS 1024          // padded col stride for ws q0 buffer
#define BB 8
#define HH 40            // register tile height (rows per wave)
#define RRF 8            // fallback rows/thread

// coef[0..8] = mu*(k1+k2)/(mu*sum(k3)) ; coef[9] = H^2/(mu*sum(k3))
// (kept ONLY for the fallback path; main path folds this into trap blocks)
__global__ void coef_kernel(const float* __restrict__ mu,
                            const float* __restrict__ k1,
                            const float* __restrict__ k2,
                            const float* __restrict__ k3,
                            float* __restrict__ coef) {
    if (threadIdx.x == 0 && blockIdx.x == 0) {
        float m = mu[0];
        float s3 = 0.0f;
        for (int t = 0; t < 9; ++t) s3 += k3[t];
        float inv_d = 1.0f / (m * s3);
        for (int t = 0; t < 9; ++t) coef[t] = m * (k1[t] + k2[t]) * inv_d;
        const float h = 1.0f / (float)(NN - 1);
        coef[9] = h * h * inv_d;
    }
}

// Wave-wide DPP shifts (64 lanes), HW-validated rounds 2/4/5 (passed).
// wshr1: lane l receives lane l-1 (lane 0 -> 0); wshl1: lane l+1 (lane 63 -> 0).
__device__ __forceinline__ float wshr1(float x) {   // left neighbor (col-1)
    return __int_as_float(__builtin_amdgcn_update_dpp(
        0, __float_as_int(x), 0x138, 0xF, 0xF, true));
}
__device__ __forceinline__ float wshl1(float x) {   // right neighbor (col+1)
    return __int_as_float(__builtin_amdgcn_update_dpp(
        0, __float_as_int(x), 0x130, 0xF, 0xF, true));
}

// Register-resident trapezoid, round-6 revision.
// R5 evidence: spill fixed (VGPR=164, WRITE=structural), waves are short
// (~7.7 us) and correct, but OccupancyPercent=9.7% (~794 resident waves of
// 3072 capacity): wall tracks a ~10 ns/wave issue/drain rate across ALL
// rounds (R0 8.3 / R2 14.5 / R4 16 / R5 9.6 ns per wave). => wave-count
// bound, not pipe bound. Fix: K tiles per wave sequentially (halves wave
// count, doubles lifetime) + coef folded into trap blocks (kills the
// serial coef dispatch). Tile body unchanged from the R5-proven kernel.
// Lane = column, row[h] = VGPR; horizontal halo via wave DPP; force tile
// in wave-private LDS; 4-tap fast path when corner/center coefs == 0
// (bitwise-identical: drops +0*x terms). Validity pyramid d>=s; global
// Dirichlet mask each step.
template <int T, int K, bool IN_PAD, bool OUT_PAD>
__global__ __launch_bounds__(256) void reg_trap_kernel(
        const float* __restrict__ yin, const float* __restrict__ f,
        const float* __restrict__ mu, const float* __restrict__ k1,
        const float* __restrict__ k2, const float* __restrict__ k3,
        float* __restrict__ yout) {
    constexpr int OUTW = 64 - 2 * T;
    constexpr int OUTH = HH - 2 * T;
    constexpr int NTC  = (MM + OUTW - 1) / OUTW;
    constexpr int NTR  = (MM + OUTH - 1) / OUTH;
    constexpr int NTOT = NTC * NTR;
    constexpr int ISTR = IN_PAD ? PS : MM;
    constexpr int OSTR = OUT_PAD ? PS : MM;

    __shared__ float frl[4][HH - 2][64];     // ~39 KB -> 3 blocks/CU at VGPR cap

    const int t    = threadIdx.x;
    const int w    = t >> 6;                 // wave id 0..3 (independent tiles)
    const int lane = t & 63;                 // column within tile
    const int b    = blockIdx.y;
    const int wid  = blockIdx.x * 4 + w;

    // ---- coef folded in (bitwise-identical op order to coef_kernel) ----
    float c[10];
    {
        float m = mu[0];
        float s3 = 0.0f;
#pragma unroll
        for (int q = 0; q < 9; ++q) s3 += k3[q];
        const float inv_d = 1.0f / (m * s3);
#pragma unroll
        for (int q = 0; q < 9; ++q) c[q] = m * (k1[q] + k2[q]) * inv_d;
        const float h = 1.0f / (float)(NN - 1);
        c[9] = h * h * inv_d;
#pragma unroll
        for (int q = 0; q < 10; ++q)
            c[q] = __int_as_float(__builtin_amdgcn_readfirstlane(
                       __float_as_int(c[q])));
    }
    // cross kernels: corners+center of (k1+k2) are exactly 0 -> 4-tap path
    const bool four = (c[0] == 0.f) && (c[2] == 0.f) && (c[4] == 0.f) &&
                      (c[6] == 0.f) && (c[8] == 0.f);

    float* fw = &frl[w][0][0];
    const float* yb = yin + (size_t)b * MM * ISTR;
    const float* fb = f   + (size_t)b * NN * NN;
    float*       yo = yout + (size_t)b * MM * OSTR;

    // ---- K tiles per wave, sequential (no unroll: keep code/regs flat) ----
#pragma unroll 1
    for (int kt = 0; kt < K; ++kt) {
        const int tile = wid * K + kt;
        if (tile >= NTOT) break;             // safe: no barriers in kernel
        const int tr = tile / NTC, tc = tile % NTC;
        const int o0r = tr * OUTH - T;       // tile origin, interior coords
        const int o0c = tc * OUTW - T;

        const int gc  = o0c + lane;
        const bool cok = (gc >= 0) && (gc < MM);
        const int gcl = min(max(gc, 0), MM - 1);   // clamped (valid) col
        const float colmask = cok ? 1.f : 0.f;

        // ---- load tile rows (clamped addr + mask; coalesced 64x4B) ----
        float row[HH];
#pragma unroll
        for (int h = 0; h < HH; ++h) {
            const int gr = o0r + h;
            const int grc = min(max(gr, 0), MM - 1);
            const float v = yb[(size_t)grc * ISTR + gcl];
            row[h] = (cok && gr >= 0 && gr < MM) ? v : 0.f;
        }

        // ---- force tile -> wave-private LDS (premult by c9, masked) ----
#pragma unroll
        for (int h = 1; h <= HH - 2; ++h) {
            const int gr = o0r + h;
            const int grc = min(max(gr, 0), MM - 1);
            const float v = fb[(size_t)(grc + 1) * NN + (gcl + 1)];
            fw[(h - 1) * 64 + lane] =
                (cok && gr >= 0 && gr < MM) ? c[9] * v : 0.f;
        }

        // wave-uniform row-validity range: gr in [0,MM) <=> h in [hlo,hhi)
        const int hlo = max(0, -o0r);
        const int hhi = min(HH, MM - o0r);

        if (four) {
            for (int s = 0; s < T; ++s) {
                float prev_old = row[0];
#pragma unroll
                for (int h = 1; h <= HH - 2; ++h) {
                    const float lc_ = wshr1(row[h]);
                    const float rc_ = wshl1(row[h]);
                    const float frv = fw[(h - 1) * 64 + lane];
                    float acc = c[1] * prev_old + c[3] * lc_
                              + c[5] * rc_ + c[7] * row[h + 1];
                    const float m = (h >= hlo && h < hhi) ? colmask : 0.f;
                    prev_old = row[h];
                    row[h] = m * acc + frv;          // Dirichlet + force
                }
            }
        } else {
            for (int s = 0; s < T; ++s) {
                float lp = wshr1(row[0]), rp = wshl1(row[0]);
                float lc_ = wshr1(row[1]), rc_ = wshl1(row[1]);
                float prev_old = row[0];
#pragma unroll
                for (int h = 1; h <= HH - 2; ++h) {
                    const float ln = wshr1(row[h + 1]);
                    const float rn = wshl1(row[h + 1]);
                    const float cur = row[h];
                    const float frv = fw[(h - 1) * 64 + lane];
                    float acc = c[0] * lp  + c[1] * prev_old  + c[2] * rp
                              + c[3] * lc_ + c[4] * cur       + c[5] * rc_
                              + c[6] * ln  + c[7] * row[h + 1] + c[8] * rn;
                    const float m = (h >= hlo && h < hhi) ? colmask : 0.f;
                    row[h] = m * acc + frv;
                    prev_old = cur;
                    lp = lc_; rp = rc_; lc_ = ln; rc_ = rn;
                }
            }
        }

        // ---- store central OUTW x OUTH ----
        {
            const bool sok = (lane >= T) && (lane < 64 - T) && (gc < MM);
#pragma unroll
            for (int h = T; h < HH - T; ++h) {
                const int orow = o0r + h;            // >= 0 by construction
                if (orow < MM && sok)
                    yo[(size_t)orow * OSTR + gc] = row[h];
            }
        }
    }
}

// ---------- fallback (round-2 proven path, used if ws too small) ----------
__global__ __launch_bounds__(256) void stencil_kernel(
        const float* __restrict__ yin, const float* __restrict__ f,
        const float* __restrict__ coef, float* __restrict__ yout) {
    const int tid = threadIdx.x;
    const int j0  = tid * 4;
    const int i0  = blockIdx.x * RRF;
    const int b   = blockIdx.y;
    const bool eL = (tid == 0), eR = (tid == 255);

    const float* yb = yin + (size_t)b * MM * MM;
    const float* fb = f   + (size_t)b * NN * NN;

    float c[10];
#pragma unroll
    for (int t = 0; t < 10; ++t) c[t] = coef[t];

    float wP[6], wC[6], wN[6];
    auto loadwin = [&](int r, float* w) {
        if (r < 0 || r >= MM) {
#pragma unroll
            for (int k = 0; k < 6; ++k) w[k] = 0.0f;
            return;
        }
        const float* row = yb + (size_t)r * MM;
        if (eR) {
            float2 ab = *(const float2*)(row + j0);
            w[0] = row[j0 - 1];
            w[1] = ab.x; w[2] = ab.y;
            w[3] = 0.0f; w[4] = 0.0f; w[5] = 0.0f;
        } else {
            float2 ab = *(const float2*)(row + j0);
            float2 cd = *(const float2*)(row + j0 + 2);
            w[0] = eL ? 0.0f : row[j0 - 1];
            w[1] = ab.x; w[2] = ab.y; w[3] = cd.x; w[4] = cd.y;
            w[5] = row[j0 + 4];
        }
    };

    loadwin(i0 - 1, wP);
    loadwin(i0,     wC);

#pragma unroll
    for (int rr = 0; rr < RRF; ++rr) {
        const int i = i0 + rr;
        if (i < MM) {
            loadwin(i + 1, wN);
            const float* frow = fb + (size_t)(i + 1) * NN;
            float fv[4];
            fv[0] = frow[j0 + 1];
            float2 fm = *(const float2*)(frow + j0 + 2);
            fv[1] = fm.x; fv[2] = fm.y;
            fv[3] = frow[j0 + 4];
            float acc[4];
#pragma unroll
            for (int k = 0; k < 4; ++k) acc[k] = c[9] * fv[k];
#pragma unroll
            for (int k = 0; k < 4; ++k) {
                acc[k] += c[0] * wP[k] + c[1] * wP[k + 1] + c[2] * wP[k + 2];
                acc[k] += c[3] * wC[k] + c[4] * wC[k + 1] + c[5] * wC[k + 2];
                acc[k] += c[6] * wN[k] + c[7] * wN[k + 1] + c[8] * wN[k + 2];
            }
            float* orow = (yout + (size_t)b * MM * MM) + (size_t)i * MM + j0;
            *(float2*)orow = make_float2(acc[0], acc[1]);
            if (!eR) *(float2*)(orow + 2) = make_float2(acc[2], acc[3]);
#pragma unroll
            for (int k = 0; k < 6; ++k) { wP[k] = wC[k]; wC[k] = wN[k]; }
        }
    }
}

extern "C" void kernel_launch(void* const* d_in, const int* in_sizes, int n_in,
                              void* d_out, int out_size, void* d_ws, size_t ws_size,
                              hipStream_t stream) {
    const float* pre = (const float*)d_in[1];
    const float* f   = (const float*)d_in[2];
    const float* mu  = (const float*)d_in[3];
    const float* k1  = (const float*)d_in[4];
    const float* k2  = (const float*)d_in[5];
    const float* k3  = (const float*)d_in[6];
    float* out = (float*)d_out;

    float* coef = (float*)d_ws;
    const size_t QE = (size_t)BB * MM * PS;               // intermediate buffer
    const size_t need = 256 + QE * sizeof(float);         // ~33.5 MB

    if (ws_size >= need) {
        float* q0 = (float*)((char*)d_ws + 256);

        // pass 1: T=6, K=2 -> out 52x28 per tile; q0 holds y_6 (padded)
        {
            constexpr int T = 6, K = 2;
            constexpr int OUTW = 64 - 2 * T, OUTH = HH - 2 * T;   // 52 x 28
            constexpr int NTC = (MM + OUTW - 1) / OUTW;           // 20
            constexpr int NTR = (MM + OUTH - 1) / OUTH;           // 37
            constexpr int NW  = (NTC * NTR + K - 1) / K;          // 370 waves
            const int nb = (NW + 3) / 4;                          // 93
            reg_trap_kernel<T, K, false, true>
                <<<dim3(nb, BB), 256, 0, stream>>>(pre, f, mu, k1, k2, k3, q0);
        }
        // pass 2: T=5, K=2 -> out 54x30 per tile; out holds y_11
        {
            constexpr int T = 5, K = 2;
            constexpr int OUTW = 64 - 2 * T, OUTH = HH - 2 * T;   // 54 x 30
            constexpr int NTC = (MM + OUTW - 1) / OUTW;           // 19
            constexpr int NTR = (MM + OUTH - 1) / OUTH;           // 35
            constexpr int NW  = (NTC * NTR + K - 1) / K;          // 333 waves
            const int nb = (NW + 3) / 4;                          // 84
            reg_trap_kernel<T, K, true, false>
                <<<dim3(nb, BB), 256, 0, stream>>>(q0, f, mu, k1, k2, k3, out);
        }
    } else {
        // fallback: round-2 proven path
        coef_kernel<<<1, 64, 0, stream>>>(mu, k1, k2, k3, coef);
        float* buf = (float*)((char*)d_ws + 256);
        dim3 grid((MM + RRF - 1) / RRF, BB);
        const float* in = pre;
        for (int t = 0; t < 11; ++t) {
            float* o = ((t & 1) == 0) ? out : buf;
            stencil_kernel<<<grid, 256, 0, stream>>>(in, f, coef, o);
            in = o;
        }
    }
}

// Round 7
// 216.403 us; speedup vs baseline: 1.4520x; 1.4520x over previous
//
#include <hip/hip_runtime.h>

#define NN 1024
#define MM 1022          // interior size
#define PS 1024          // padded col stride for ws q0 buffer
#define BB 8
#define HH 40            // register tile height (rows per wave)
#define RRF 8            // fallback rows/thread

// coef[0..8] = mu*(k1+k2)/(mu*sum(k3)) ; coef[9] = H^2/(mu*sum(k3))
// (kept ONLY for the fallback path; main path folds this into trap blocks)
__global__ void coef_kernel(const float* __restrict__ mu,
                            const float* __restrict__ k1,
                            const float* __restrict__ k2,
                            const float* __restrict__ k3,
                            float* __restrict__ coef) {
    if (threadIdx.x == 0 && blockIdx.x == 0) {
        float m = mu[0];
        float s3 = 0.0f;
        for (int t = 0; t < 9; ++t) s3 += k3[t];
        float inv_d = 1.0f / (m * s3);
        for (int t = 0; t < 9; ++t) coef[t] = m * (k1[t] + k2[t]) * inv_d;
        const float h = 1.0f / (float)(NN - 1);
        coef[9] = h * h * inv_d;
    }
}

// Wave-wide DPP shifts (64 lanes), HW-validated rounds 2/4/5/6 (passed).
// wshr1: lane l receives lane l-1 (lane 0 -> 0); wshl1: lane l+1 (lane 63 -> 0).
__device__ __forceinline__ float wshr1(float x) {   // left neighbor (col-1)
    return __int_as_float(__builtin_amdgcn_update_dpp(
        0, __float_as_int(x), 0x138, 0xF, 0xF, true));
}
__device__ __forceinline__ float wshl1(float x) {   // right neighbor (col+1)
    return __int_as_float(__builtin_amdgcn_update_dpp(
        0, __float_as_int(x), 0x130, 0xF, 0xF, true));
}

// Register-resident trapezoid, round-7 revision = R5 body + R6 coef fold-in.
// R6 evidence: K=2 serialization tripled per-tile stall (same integrated
// VALU work, 2.8x wall) -> revert to ONE tile per wave (R5-proven 57us).
// R0-R6 gap accounting: rounds with the separate 1-block coef_kernel in
// the graph carry +65..104us of non-dispatch wall; R6 (folded) ~0 -> keep
// the fold-in (bitwise-identical op order to coef_kernel).
// Lane = column, row[h] = VGPR; horizontal halo via wave DPP; force tile
// in wave-private LDS; 4-tap fast path when corner/center coefs == 0
// (bitwise-identical: drops +0*x terms). Validity pyramid d>=s; global
// Dirichlet mask each step. Zero barriers, zero __syncthreads.
template <int T, bool IN_PAD, bool OUT_PAD>
__global__ __launch_bounds__(256) void reg_trap_kernel(
        const float* __restrict__ yin, const float* __restrict__ f,
        const float* __restrict__ mu, const float* __restrict__ k1,
        const float* __restrict__ k2, const float* __restrict__ k3,
        float* __restrict__ yout) {
    constexpr int OUTW = 64 - 2 * T;
    constexpr int OUTH = HH - 2 * T;
    constexpr int NTC  = (MM + OUTW - 1) / OUTW;
    constexpr int NTR  = (MM + OUTH - 1) / OUTH;
    constexpr int NTOT = NTC * NTR;
    constexpr int ISTR = IN_PAD ? PS : MM;
    constexpr int OSTR = OUT_PAD ? PS : MM;

    __shared__ float frl[4][HH - 2][64];     // ~39 KB

    const int t    = threadIdx.x;
    const int w    = t >> 6;                 // wave id 0..3 (independent tiles)
    const int lane = t & 63;                 // column within tile
    const int b    = blockIdx.y;
    const int tile = blockIdx.x * 4 + w;     // one tile per wave (R5-proven)
    if (tile >= NTOT) return;                // safe: no barriers in kernel

    // ---- coef folded in (bitwise-identical op order to coef_kernel) ----
    float c[10];
    {
        float m = mu[0];
        float s3 = 0.0f;
#pragma unroll
        for (int q = 0; q < 9; ++q) s3 += k3[q];
        const float inv_d = 1.0f / (m * s3);
#pragma unroll
        for (int q = 0; q < 9; ++q) c[q] = m * (k1[q] + k2[q]) * inv_d;
        const float h = 1.0f / (float)(NN - 1);
        c[9] = h * h * inv_d;
#pragma unroll
        for (int q = 0; q < 10; ++q)
            c[q] = __int_as_float(__builtin_amdgcn_readfirstlane(
                       __float_as_int(c[q])));
    }
    // cross kernels: corners+center of (k1+k2) are exactly 0 -> 4-tap path
    const bool four = (c[0] == 0.f) && (c[2] == 0.f) && (c[4] == 0.f) &&
                      (c[6] == 0.f) && (c[8] == 0.f);

    const int tr = tile / NTC, tc = tile % NTC;
    const int o0r = tr * OUTH - T;           // tile origin, interior coords
    const int o0c = tc * OUTW - T;

    const int gc  = o0c + lane;
    const bool cok = (gc >= 0) && (gc < MM);
    const int gcl = min(max(gc, 0), MM - 1); // clamped col (always-valid addr)
    const float colmask = cok ? 1.f : 0.f;

    const float* yb = yin + (size_t)b * MM * ISTR;
    const float* fb = f   + (size_t)b * NN * NN;
    float*       yo = yout + (size_t)b * MM * OSTR;
    float* fw = &frl[w][0][0];

    // ---- load tile rows (clamped addr + mask; coalesced 64x4B per row) ----
    float row[HH];
#pragma unroll
    for (int h = 0; h < HH; ++h) {
        const int gr = o0r + h;
        const int grc = min(max(gr, 0), MM - 1);
        const float v = yb[(size_t)grc * ISTR + gcl];
        row[h] = (cok && gr >= 0 && gr < MM) ? v : 0.f;
    }

    // ---- force tile -> wave-private LDS (premultiplied by c9, masked) ----
#pragma unroll
    for (int h = 1; h <= HH - 2; ++h) {
        const int gr = o0r + h;
        const int grc = min(max(gr, 0), MM - 1);
        const float v = fb[(size_t)(grc + 1) * NN + (gcl + 1)];
        fw[(h - 1) * 64 + lane] =
            (cok && gr >= 0 && gr < MM) ? c[9] * v : 0.f;
    }

    // wave-uniform row-validity range: gr in [0,MM) <=> h in [hlo,hhi)
    const int hlo = max(0, -o0r);
    const int hhi = min(HH, MM - o0r);

    if (four) {
        for (int s = 0; s < T; ++s) {
            float prev_old = row[0];
#pragma unroll
            for (int h = 1; h <= HH - 2; ++h) {
                const float lc_ = wshr1(row[h]);
                const float rc_ = wshl1(row[h]);
                const float frv = fw[(h - 1) * 64 + lane];
                float acc = c[1] * prev_old + c[3] * lc_
                          + c[5] * rc_ + c[7] * row[h + 1];
                const float m = (h >= hlo && h < hhi) ? colmask : 0.f;
                prev_old = row[h];
                row[h] = m * acc + frv;              // Dirichlet + force
            }
        }
    } else {
        for (int s = 0; s < T; ++s) {
            float lp = wshr1(row[0]), rp = wshl1(row[0]);
            float lc_ = wshr1(row[1]), rc_ = wshl1(row[1]);
            float prev_old = row[0];
#pragma unroll
            for (int h = 1; h <= HH - 2; ++h) {
                const float ln = wshr1(row[h + 1]);
                const float rn = wshl1(row[h + 1]);
                const float cur = row[h];
                const float frv = fw[(h - 1) * 64 + lane];
                float acc = c[0] * lp  + c[1] * prev_old  + c[2] * rp
                          + c[3] * lc_ + c[4] * cur       + c[5] * rc_
                          + c[6] * ln  + c[7] * row[h + 1] + c[8] * rn;
                const float m = (h >= hlo && h < hhi) ? colmask : 0.f;
                row[h] = m * acc + frv;
                prev_old = cur;
                lp = lc_; rp = rc_; lc_ = ln; rc_ = rn;
            }
        }
    }

    // ---- store central OUTW x OUTH ----
    {
        const bool sok = (lane >= T) && (lane < 64 - T) && (gc < MM);
#pragma unroll
        for (int h = T; h < HH - T; ++h) {
            const int orow = o0r + h;                // >= 0 by construction
            if (orow < MM && sok)
                yo[(size_t)orow * OSTR + gc] = row[h];
        }
    }
}

// ---------- fallback (round-2 proven path, used if ws too small) ----------
__global__ __launch_bounds__(256) void stencil_kernel(
        const float* __restrict__ yin, const float* __restrict__ f,
        const float* __restrict__ coef, float* __restrict__ yout) {
    const int tid = threadIdx.x;
    const int j0  = tid * 4;
    const int i0  = blockIdx.x * RRF;
    const int b   = blockIdx.y;
    const bool eL = (tid == 0), eR = (tid == 255);

    const float* yb = yin + (size_t)b * MM * MM;
    const float* fb = f   + (size_t)b * NN * NN;

    float c[10];
#pragma unroll
    for (int t = 0; t < 10; ++t) c[t] = coef[t];

    float wP[6], wC[6], wN[6];
    auto loadwin = [&](int r, float* w) {
        if (r < 0 || r >= MM) {
#pragma unroll
            for (int k = 0; k < 6; ++k) w[k] = 0.0f;
            return;
        }
        const float* row = yb + (size_t)r * MM;
        if (eR) {
            float2 ab = *(const float2*)(row + j0);
            w[0] = row[j0 - 1];
            w[1] = ab.x; w[2] = ab.y;
            w[3] = 0.0f; w[4] = 0.0f; w[5] = 0.0f;
        } else {
            float2 ab = *(const float2*)(row + j0);
            float2 cd = *(const float2*)(row + j0 + 2);
            w[0] = eL ? 0.0f : row[j0 - 1];
            w[1] = ab.x; w[2] = ab.y; w[3] = cd.x; w[4] = cd.y;
            w[5] = row[j0 + 4];
        }
    };

    loadwin(i0 - 1, wP);
    loadwin(i0,     wC);

#pragma unroll
    for (int rr = 0; rr < RRF; ++rr) {
        const int i = i0 + rr;
        if (i < MM) {
            loadwin(i + 1, wN);
            const float* frow = fb + (size_t)(i + 1) * NN;
            float fv[4];
            fv[0] = frow[j0 + 1];
            float2 fm = *(const float2*)(frow + j0 + 2);
            fv[1] = fm.x; fv[2] = fm.y;
            fv[3] = frow[j0 + 4];
            float acc[4];
#pragma unroll
            for (int k = 0; k < 4; ++k) acc[k] = c[9] * fv[k];
#pragma unroll
            for (int k = 0; k < 4; ++k) {
                acc[k] += c[0] * wP[k] + c[1] * wP[k + 1] + c[2] * wP[k + 2];
                acc[k] += c[3] * wC[k] + c[4] * wC[k + 1] + c[5] * wC[k + 2];
                acc[k] += c[6] * wN[k] + c[7] * wN[k + 1] + c[8] * wN[k + 2];
            }
            float* orow = (yout + (size_t)b * MM * MM) + (size_t)i * MM + j0;
            *(float2*)orow = make_float2(acc[0], acc[1]);
            if (!eR) *(float2*)(orow + 2) = make_float2(acc[2], acc[3]);
#pragma unroll
            for (int k = 0; k < 6; ++k) { wP[k] = wC[k]; wC[k] = wN[k]; }
        }
    }
}

extern "C" void kernel_launch(void* const* d_in, const int* in_sizes, int n_in,
                              void* d_out, int out_size, void* d_ws, size_t ws_size,
                              hipStream_t stream) {
    const float* pre = (const float*)d_in[1];
    const float* f   = (const float*)d_in[2];
    const float* mu  = (const float*)d_in[3];
    const float* k1  = (const float*)d_in[4];
    const float* k2  = (const float*)d_in[5];
    const float* k3  = (const float*)d_in[6];
    float* out = (float*)d_out;

    float* coef = (float*)d_ws;
    const size_t QE = (size_t)BB * MM * PS;               // intermediate buffer
    const size_t need = 256 + QE * sizeof(float);         // ~33.5 MB

    if (ws_size >= need) {
        float* q0 = (float*)((char*)d_ws + 256);

        // pass 1: T=6 -> out 52x28 per tile; q0 holds y_6 (padded stride)
        {
            constexpr int T = 6;
            constexpr int OUTW = 64 - 2 * T, OUTH = HH - 2 * T;   // 52 x 28
            constexpr int NTC = (MM + OUTW - 1) / OUTW;           // 20
            constexpr int NTR = (MM + OUTH - 1) / OUTH;           // 37
            const int nb = (NTC * NTR + 3) / 4;                   // 185
            reg_trap_kernel<T, false, true>
                <<<dim3(nb, BB), 256, 0, stream>>>(pre, f, mu, k1, k2, k3, q0);
        }
        // pass 2: T=5 -> out 54x30 per tile; out holds y_11
        {
            constexpr int T = 5;
            constexpr int OUTW = 64 - 2 * T, OUTH = HH - 2 * T;   // 54 x 30
            constexpr int NTC = (MM + OUTW - 1) / OUTW;           // 19
            constexpr int NTR = (MM + OUTH - 1) / OUTH;           // 35
            const int nb = (NTC * NTR + 3) / 4;                   // 167
            reg_trap_kernel<T, true, false>
                <<<dim3(nb, BB), 256, 0, stream>>>(q0, f, mu, k1, k2, k3, out);
        }
    } else {
        // fallback: round-2 proven path
        coef_kernel<<<1, 64, 0, stream>>>(mu, k1, k2, k3, coef);
        float* buf = (float*)((char*)d_ws + 256);
        dim3 grid((MM + RRF - 1) / RRF, BB);
        const float* in = pre;
        for (int t = 0; t < 11; ++t) {
            float* o = ((t & 1) == 0) ? out : buf;
            stencil_kernel<<<grid, 256, 0, stream>>>(in, f, coef, o);
            in = o;
        }
    }
}